// Round 10
// baseline (90.016 us; speedup 1.0000x reference)
//
#include <hip/hip_runtime.h>

#define NT 256

namespace {
constexpr int C = 8, G = 8, M = 256, NPT = 1023;
constexpr int PD = 12;   // padded per-node float stride (48 B): float4-aligned, spreads banks

__device__ __forceinline__ float rcpf(float x) { return __builtin_amdgcn_rcpf(x); }

#define LD8(dst, srcp) do {                                              \
    const float4 _a = *(const float4*)(srcp);                            \
    const float4 _b = *(const float4*)((srcp) + 4);                      \
    (dst)[0]=_a.x;(dst)[1]=_a.y;(dst)[2]=_a.z;(dst)[3]=_a.w;             \
    (dst)[4]=_b.x;(dst)[5]=_b.y;(dst)[6]=_b.z;(dst)[7]=_b.w; } while(0)

#define ST8(dstp, src) do {                                              \
    *(float4*)(dstp)       = make_float4((src)[0],(src)[1],(src)[2],(src)[3]); \
    *(float4*)((dstp) + 4) = make_float4((src)[4],(src)[5],(src)[6],(src)[7]); } while(0)

__global__ __launch_bounds__(NT, 2)
void htmm_fused(const float* __restrict__ Ag, const float* __restrict__ Bg,
                const float* __restrict__ Pig, const int* __restrict__ xg,
                float* __restrict__ out)
{
    __shared__ int xs[NPT + 1];
    __shared__ __align__(16) float smBt[M][PD];    // softmax(B)^T : [symbol][state]
    __shared__ __align__(16) float logBt[M][PD];   // log softmax(B)^T
    __shared__ __align__(16) float bet[511][PD];   // beta nodes 0..510; eps in place downward
    __shared__ __align__(16) float tbe[255][PD];   // t_beta nodes 0..254
    __shared__ __align__(16) float smA_s[C][C];
    __shared__ __align__(16) float alA_s[C][C];    // smA * log smA
    __shared__ float pi_s[2][C];
    __shared__ float red[4];

    const int tid  = threadIdx.x;
    const int wv   = tid >> 6, lane = tid & 63;
    const int tree = blockIdx.x >> 3, g = blockIdx.x & 7;

    // ---------- P0: stage x, build transposed softmax tables ----------
    for (int n = tid; n < NPT; n += NT) xs[n] = xg[tree * NPT + n];
    {   // emission rows: wave wv owns rows 2wv, 2wv+1 (one per half-wave); raw in [-5,5]
        const int i  = 2 * wv + (lane >> 5);
        const int c0 = lane & 31;
        float raw[8], ex[8], ssum = 0.f;
        #pragma unroll
        for (int t = 0; t < 8; ++t) {
            raw[t] = Bg[(i * M + c0 + 32 * t) * G + g];
            ex[t]  = __expf(raw[t]);
            ssum  += ex[t];
        }
        #pragma unroll
        for (int m = 1; m <= 16; m <<= 1) ssum += __shfl_xor(ssum, m);
        const float inv = rcpf(ssum), ls = __logf(ssum);
        #pragma unroll
        for (int t = 0; t < 8; ++t) {
            smBt [c0 + 32 * t][i] = ex[t] * inv;
            logBt[c0 + 32 * t][i] = raw[t] - ls;
        }
    }
    if (wv == 0) {                       // A softmax over parent dim i; lane=(i,j)
        const int si = lane >> 3, qj = lane & 7;
        const float raw = Ag[(si * C + qj) * G + g];
        float e = __expf(raw), S = e;
        #pragma unroll
        for (int m = 8; m <= 32; m <<= 1) S += __shfl_xor(S, m);
        const float v = e / S;
        smA_s[si][qj] = v;
        alA_s[si][qj] = v * (raw - __logf(S));
    } else if (wv == 1 && lane < C) {    // Pi softmax
        const float raw = Pig[lane * G + g];
        float e = __expf(raw), S = e;
        #pragma unroll
        for (int m = 1; m <= 4; m <<= 1) S += __shfl_xor(S, m);
        pi_s[0][lane] = e / S;
        pi_s[1][lane] = raw - __logf(S);
    }
    __syncthreads();

    // ---------- per-thread register tables (broadcast LDS reads: conflict-free) ----------
    float Ae[64], ALAe[64], piR[8], lPi[8];
    #pragma unroll
    for (int i = 0; i < 8; ++i) {
        float ar[8], lr[8];
        LD8(ar, &smA_s[i][0]);
        LD8(lr, &alA_s[i][0]);
        #pragma unroll
        for (int j = 0; j < 8; ++j) { Ae[8*i+j] = ar[j]; ALAe[8*i+j] = lr[j]; }
    }
    #pragma unroll
    for (int i = 0; i < 8; ++i) { piR[i] = pi_s[0][i]; lPi[i] = pi_s[1][i]; }

    // ---------- P1: bottom subtree (level-8 node + 2 leaves) fully in registers ----------
    const int nd8 = 255 + tid;                       // this thread's level-8 node
    const int xv8 = xs[nd8], xvL = xs[2*nd8 + 1], xvR = xs[2*nd8 + 2];
    float bl0[8], bl1[8], tb8[8], b8[8];
    {
        float sm[8], u[8], S, inv;
        LD8(sm, &smBt[xvL][0]);                      // leaf L
        S = 0.f;
        #pragma unroll
        for (int i = 0; i < 8; ++i) { u[i] = piR[i] * sm[i]; S += u[i]; }
        inv = rcpf(S);
        #pragma unroll
        for (int i = 0; i < 8; ++i) bl0[i] = u[i] * inv;

        LD8(sm, &smBt[xvR][0]);                      // leaf R
        S = 0.f;
        #pragma unroll
        for (int i = 0; i < 8; ++i) { u[i] = piR[i] * sm[i]; S += u[i]; }
        inv = rcpf(S);
        #pragma unroll
        for (int i = 0; i < 8; ++i) bl1[i] = u[i] * inv;

        float c[8];                                  // level-8 node
        #pragma unroll
        for (int j = 0; j < 8; ++j) c[j] = bl0[j] + bl1[j];
        #pragma unroll
        for (int i = 0; i < 8; ++i) {
            float t = 0.f;
            #pragma unroll
            for (int j = 0; j < 8; ++j) t += Ae[8*i+j] * c[j];
            tb8[i] = 0.5f * t;
        }
        LD8(sm, &smBt[xv8][0]);
        S = 0.f;
        #pragma unroll
        for (int i = 0; i < 8; ++i) { u[i] = tb8[i] * sm[i]; S += u[i]; }
        inv = rcpf(S);
        #pragma unroll
        for (int i = 0; i < 8; ++i) b8[i] = u[i] * inv;
        ST8(&bet[nd8][0], b8);
    }
    __syncthreads();

    // ---------- P2: upper tree upward, thread-per-node per level ----------
    for (int lvl = 7; lvl >= 0; --lvl) {
        const int cnt = 1 << lvl, base = cnt - 1;
        if (tid < cnt) {
            const int p = base + tid, cl = 2*p + 1;
            float lb_[8], rb_[8], cb[8];
            LD8(lb_, &bet[cl][0]);
            LD8(rb_, &bet[cl + 1][0]);
            #pragma unroll
            for (int j = 0; j < 8; ++j) cb[j] = lb_[j] + rb_[j];
            float tb[8];
            #pragma unroll
            for (int i = 0; i < 8; ++i) {
                float t = 0.f;
                #pragma unroll
                for (int j = 0; j < 8; ++j) t += Ae[8*i+j] * cb[j];
                tb[i] = 0.5f * t;
            }
            ST8(&tbe[p][0], tb);
            float sm[8], u[8], S = 0.f;
            LD8(sm, &smBt[xs[p]][0]);
            #pragma unroll
            for (int i = 0; i < 8; ++i) { u[i] = tb[i] * sm[i]; S += u[i]; }
            const float inv = rcpf(S);
            float b[8];
            #pragma unroll
            for (int i = 0; i < 8; ++i) b[i] = u[i] * inv;
            ST8(&bet[p][0], b);
        }
        __syncthreads();
    }

    float acc = 0.f;
    if (tid == 0) {                                  // root B-term (eps[root] = beta[root])
        float b0[8], lb[8];
        LD8(b0, &bet[0][0]);
        LD8(lb, &logBt[xs[0]][0]);
        #pragma unroll
        for (int j = 0; j < 8; ++j) acc += b0[j] * lb[j];
    }

    // ---------- P3: upper tree downward (child threads recompute parent w) ----------
    for (int dc = 1; dc <= 7; ++dc) {
        const int cnt = 1 << dc, base = cnt - 1;
        if (tid < cnt) {
            const int ch = base + tid, p = (ch - 1) >> 1;
            float ep[8], tp[8], w[8];
            LD8(ep, &bet[p][0]);
            LD8(tp, &tbe[p][0]);
            #pragma unroll
            for (int i = 0; i < 8; ++i) w[i] = ep[i] * rcpf(tp[i]);
            float es[8] = {0,0,0,0,0,0,0,0}, ts[8] = {0,0,0,0,0,0,0,0};
            #pragma unroll
            for (int i = 0; i < 8; ++i) {
                #pragma unroll
                for (int j = 0; j < 8; ++j) {
                    es[j] += w[i] * Ae[8*i+j];
                    ts[j] += w[i] * ALAe[8*i+j];
                }
            }
            float bc[8], lb[8], ev[8];
            LD8(bc, &bet[ch][0]);
            LD8(lb, &logBt[xs[ch]][0]);
            float a1 = 0.f, a2 = 0.f;
            #pragma unroll
            for (int j = 0; j < 8; ++j) {
                ev[j] = bc[j] * es[j];
                a1 += bc[j] * ts[j];
                a2 += ev[j] * lb[j];
            }
            acc += 0.5f * a1 + a2;
            ST8(&bet[ch][0], ev);                    // eps in place
        }
        __syncthreads();
    }

    // ---------- P4: bottom subtree downward, registers only ----------
    {
        const int p7 = (nd8 - 1) >> 1;
        float ep[8], tp[8], w[8];
        LD8(ep, &bet[p7][0]);
        LD8(tp, &tbe[p7][0]);
        #pragma unroll
        for (int i = 0; i < 8; ++i) w[i] = ep[i] * rcpf(tp[i]);
        float es[8] = {0,0,0,0,0,0,0,0}, ts[8] = {0,0,0,0,0,0,0,0};
        #pragma unroll
        for (int i = 0; i < 8; ++i) {
            #pragma unroll
            for (int j = 0; j < 8; ++j) {
                es[j] += w[i] * Ae[8*i+j];
                ts[j] += w[i] * ALAe[8*i+j];
            }
        }
        float lb[8], ev8[8], w8[8];
        LD8(lb, &logBt[xv8][0]);
        float a1 = 0.f, a2 = 0.f;
        #pragma unroll
        for (int j = 0; j < 8; ++j) {
            ev8[j] = b8[j] * es[j];
            a1 += b8[j] * ts[j];
            a2 += ev8[j] * lb[j];
        }
        acc += 0.5f * a1 + a2;
        #pragma unroll
        for (int i = 0; i < 8; ++i) w8[i] = ev8[i] * rcpf(tb8[i]);

        // shared es/ts for the two leaves (same parent w8)
        float es2[8] = {0,0,0,0,0,0,0,0}, ts2[8] = {0,0,0,0,0,0,0,0};
        #pragma unroll
        for (int i = 0; i < 8; ++i) {
            #pragma unroll
            for (int j = 0; j < 8; ++j) {
                es2[j] += w8[i] * Ae[8*i+j];
                ts2[j] += w8[i] * ALAe[8*i+j];
            }
        }
        LD8(lb, &logBt[xvL][0]);
        a1 = 0.f; a2 = 0.f;
        #pragma unroll
        for (int j = 0; j < 8; ++j) {
            const float ev = bl0[j] * es2[j];
            a1 += bl0[j] * ts2[j];
            a2 += ev * (lb[j] + lPi[j]);
        }
        acc += 0.5f * a1 + a2;
        LD8(lb, &logBt[xvR][0]);
        a1 = 0.f; a2 = 0.f;
        #pragma unroll
        for (int j = 0; j < 8; ++j) {
            const float ev = bl1[j] * es2[j];
            a1 += bl1[j] * ts2[j];
            a2 += ev * (lb[j] + lPi[j]);
        }
        acc += 0.5f * a1 + a2;
    }

    // ---------- P5: block reduction, out = -ll ----------
    #pragma unroll
    for (int m = 1; m <= 32; m <<= 1) acc += __shfl_xor(acc, m);
    if (lane == 0) red[wv] = acc;
    __syncthreads();
    if (tid == 0) out[blockIdx.x] = -(red[0] + red[1] + red[2] + red[3]);
}
} // namespace

extern "C" void kernel_launch(void* const* d_in, const int* in_sizes, int n_in,
                              void* d_out, int out_size, void* d_ws, size_t ws_size,
                              hipStream_t stream) {
    const float* A  = (const float*)d_in[0];
    const float* Bm = (const float*)d_in[1];
    const float* Pi = (const float*)d_in[2];
    const int*   x  = (const int*)d_in[3];
    float* o = (float*)d_out;
    hipLaunchKernelGGL(htmm_fused, dim3(64 * 8), dim3(NT), 0, stream,
                       A, Bm, Pi, x, o);
}

// Round 14
// 77.993 us; speedup vs baseline: 1.1542x; 1.1542x over previous
//
#include <hip/hip_runtime.h>

#define NT 256

namespace {
constexpr int C = 8, G = 8, M = 256, NPT = 1023;
constexpr int PD = 12;   // padded per-node float stride (48 B), float4-aligned

__device__ __forceinline__ float rcpf(float x) { return __builtin_amdgcn_rcpf(x); }

#define LD8(dst, srcp) do {                                              \
    const float4 _a = *(const float4*)(srcp);                            \
    const float4 _b = *(const float4*)((srcp) + 4);                      \
    (dst)[0]=_a.x;(dst)[1]=_a.y;(dst)[2]=_a.z;(dst)[3]=_a.w;             \
    (dst)[4]=_b.x;(dst)[5]=_b.y;(dst)[6]=_b.z;(dst)[7]=_b.w; } while(0)

#define ST8(dstp, src) do {                                              \
    *(float4*)(dstp)       = make_float4((src)[0],(src)[1],(src)[2],(src)[3]); \
    *(float4*)((dstp) + 4) = make_float4((src)[4],(src)[5],(src)[6],(src)[7]); } while(0)

__global__ __launch_bounds__(NT, 2)
void htmm_fused(const float* __restrict__ Ag, const float* __restrict__ Bg,
                const float* __restrict__ Pig, const int* __restrict__ xg,
                float* __restrict__ out)
{
    __shared__ int xs[NPT + 1];
    __shared__ __align__(16) float smBt[M][PD];    // softmax(B)^T : [symbol][state]
    __shared__ __align__(16) float logBt[M][PD];   // log softmax(B)^T
    __shared__ __align__(16) float bet[511][PD];   // beta 0..510; eps in place downward
    __shared__ __align__(16) float tbe[255][PD];   // t_beta 0..254
    __shared__ __align__(16) float smA_s[C][C];    // block-uniform, read as broadcast rows
    __shared__ __align__(16) float alA_s[C][C];    // smA * log smA
    __shared__ float pi_s[2][C];
    __shared__ float red[4];

    const int tid  = threadIdx.x;
    const int wv   = tid >> 6, lane = tid & 63;
    const int tree = blockIdx.x >> 3, g = blockIdx.x & 7;

    // ---------- P0: stage x, build transposed softmax tables ----------
    for (int n = tid; n < NPT; n += NT) xs[n] = xg[tree * NPT + n];
    {   // emission rows: wave wv owns rows 2wv, 2wv+1; raw in [-5,5]
        const int i  = 2 * wv + (lane >> 5);
        const int c0 = lane & 31;
        float raw[8], ex[8], ssum = 0.f;
        #pragma unroll
        for (int t = 0; t < 8; ++t) {
            raw[t] = Bg[(i * M + c0 + 32 * t) * G + g];
            ex[t]  = __expf(raw[t]);
            ssum  += ex[t];
        }
        #pragma unroll
        for (int m = 1; m <= 16; m <<= 1) ssum += __shfl_xor(ssum, m);
        const float inv = rcpf(ssum), ls = __logf(ssum);
        #pragma unroll
        for (int t = 0; t < 8; ++t) {
            smBt [c0 + 32 * t][i] = ex[t] * inv;
            logBt[c0 + 32 * t][i] = raw[t] - ls;
        }
    }
    if (wv == 0) {                       // A softmax over parent dim i; lane=(i,j)
        const int si = lane >> 3, qj = lane & 7;
        const float raw = Ag[(si * C + qj) * G + g];
        float e = __expf(raw), S = e;
        #pragma unroll
        for (int m = 8; m <= 32; m <<= 1) S += __shfl_xor(S, m);
        const float v = e / S;
        smA_s[si][qj] = v;
        alA_s[si][qj] = v * (raw - __logf(S));
    } else if (wv == 1 && lane < C) {    // Pi softmax
        const float raw = Pig[lane * G + g];
        float e = __expf(raw), S = e;
        #pragma unroll
        for (int m = 1; m <= 4; m <<= 1) S += __shfl_xor(S, m);
        pi_s[0][lane] = e / S;
        pi_s[1][lane] = raw - __logf(S);
    }
    __syncthreads();

    // einsum helpers: A rows are block-uniform -> LDS broadcast reads, no reg tables
    auto trans_up = [&](const float* c8, float* tb) {   // tb[i] = 0.5*dot(Arow_i, c8)
        #pragma unroll
        for (int i = 0; i < 8; ++i) {
            float r[8]; LD8(r, &smA_s[i][0]);
            float t = 0.f;
            #pragma unroll
            for (int j = 0; j < 8; ++j) t += r[j] * c8[j];
            tb[i] = 0.5f * t;
        }
    };
    auto wexp = [&](const float* w, float* es, float* ts) { // es=w^T A, ts=w^T (A.logA)
        #pragma unroll
        for (int j = 0; j < 8; ++j) { es[j] = 0.f; ts[j] = 0.f; }
        #pragma unroll
        for (int i = 0; i < 8; ++i) {
            float a[8], l[8];
            LD8(a, &smA_s[i][0]);
            LD8(l, &alA_s[i][0]);
            #pragma unroll
            for (int j = 0; j < 8; ++j) { es[j] += w[i] * a[j]; ts[j] += w[i] * l[j]; }
        }
    };

    float acc = 0.f;

    // ---------- P1: bottom subtree (level-8 node + 2 leaves) in registers ----------
    const int nd8 = 255 + tid;
    const int xv8 = xs[nd8], xvL = xs[2*nd8 + 1], xvR = xs[2*nd8 + 2];
    float bl0[8], bl1[8], tb8[8], b8[8];
    {
        float piR[8]; LD8(piR, &pi_s[0][0]);
        float sm[8], u[8], S, inv;
        LD8(sm, &smBt[xvL][0]);
        S = 0.f;
        #pragma unroll
        for (int i = 0; i < 8; ++i) { u[i] = piR[i] * sm[i]; S += u[i]; }
        inv = rcpf(S);
        #pragma unroll
        for (int i = 0; i < 8; ++i) bl0[i] = u[i] * inv;

        LD8(sm, &smBt[xvR][0]);
        S = 0.f;
        #pragma unroll
        for (int i = 0; i < 8; ++i) { u[i] = piR[i] * sm[i]; S += u[i]; }
        inv = rcpf(S);
        #pragma unroll
        for (int i = 0; i < 8; ++i) bl1[i] = u[i] * inv;

        float c[8];
        #pragma unroll
        for (int j = 0; j < 8; ++j) c[j] = bl0[j] + bl1[j];
        trans_up(c, tb8);
        LD8(sm, &smBt[xv8][0]);
        S = 0.f;
        #pragma unroll
        for (int i = 0; i < 8; ++i) { u[i] = tb8[i] * sm[i]; S += u[i]; }
        inv = rcpf(S);
        #pragma unroll
        for (int i = 0; i < 8; ++i) b8[i] = u[i] * inv;
        ST8(&bet[nd8][0], b8);
    }
    __syncthreads();

    // ---------- P2: upper tree upward, thread-per-node ----------
    for (int lvl = 7; lvl >= 0; --lvl) {
        const int cnt = 1 << lvl, base = cnt - 1;
        if (tid < cnt) {
            const int p = base + tid, cl = 2*p + 1;
            float lb_[8], rb_[8], cb[8], tb[8];
            LD8(lb_, &bet[cl][0]);
            LD8(rb_, &bet[cl + 1][0]);
            #pragma unroll
            for (int j = 0; j < 8; ++j) cb[j] = lb_[j] + rb_[j];
            trans_up(cb, tb);
            ST8(&tbe[p][0], tb);
            float sm[8], u[8], S = 0.f;
            LD8(sm, &smBt[xs[p]][0]);
            #pragma unroll
            for (int i = 0; i < 8; ++i) { u[i] = tb[i] * sm[i]; S += u[i]; }
            const float inv = rcpf(S);
            float b[8];
            #pragma unroll
            for (int i = 0; i < 8; ++i) b[i] = u[i] * inv;
            ST8(&bet[p][0], b);
        }
        __syncthreads();
    }

    if (tid == 0) {                      // root B-term (eps[root] = beta[root])
        float b0[8], lb[8];
        LD8(b0, &bet[0][0]);
        LD8(lb, &logBt[xs[0]][0]);
        #pragma unroll
        for (int j = 0; j < 8; ++j) acc += b0[j] * lb[j];
    }

    // ---------- P3: upper tree downward, thread-per-PARENT (handles both children) ----------
    for (int dc = 1; dc <= 7; ++dc) {
        const int cntp = 1 << (dc - 1), basep = cntp - 1;
        if (tid < cntp) {
            const int p = basep + tid;
            float ep[8], tp[8], w[8], es[8], ts[8];
            LD8(ep, &bet[p][0]);
            LD8(tp, &tbe[p][0]);
            #pragma unroll
            for (int i = 0; i < 8; ++i) w[i] = ep[i] * rcpf(tp[i]);
            wexp(w, es, ts);
            #pragma unroll
            for (int cc = 0; cc < 2; ++cc) {
                const int ch = 2*p + 1 + cc;
                float bc[8], lb[8], ev[8];
                LD8(bc, &bet[ch][0]);
                LD8(lb, &logBt[xs[ch]][0]);
                float a1 = 0.f, a2 = 0.f;
                #pragma unroll
                for (int j = 0; j < 8; ++j) {
                    ev[j] = bc[j] * es[j];
                    a1 += bc[j] * ts[j];
                    a2 += ev[j] * lb[j];
                }
                acc += 0.5f * a1 + a2;
                ST8(&bet[ch][0], ev);    // eps in place
            }
        }
        __syncthreads();
    }

    // ---------- P4: bottom subtree downward (level-8 node + leaves), per thread ----------
    {
        const int p7 = (nd8 - 1) >> 1;
        float ep[8], tp[8], w[8], es[8], ts[8];
        LD8(ep, &bet[p7][0]);            // eps of level-7 parent
        LD8(tp, &tbe[p7][0]);
        #pragma unroll
        for (int i = 0; i < 8; ++i) w[i] = ep[i] * rcpf(tp[i]);
        wexp(w, es, ts);                 // broadcast rows: uniform across wave

        float lb[8], ev8[8], w8[8];
        LD8(lb, &logBt[xv8][0]);
        float a1 = 0.f, a2 = 0.f;
        #pragma unroll
        for (int j = 0; j < 8; ++j) {
            ev8[j] = b8[j] * es[j];
            a1 += b8[j] * ts[j];
            a2 += ev8[j] * lb[j];
        }
        acc += 0.5f * a1 + a2;
        #pragma unroll
        for (int i = 0; i < 8; ++i) w8[i] = ev8[i] * rcpf(tb8[i]);

        wexp(w8, es, ts);                // shared by both leaves
        float lPi[8]; LD8(lPi, &pi_s[1][0]);
        LD8(lb, &logBt[xvL][0]);
        a1 = 0.f; a2 = 0.f;
        #pragma unroll
        for (int j = 0; j < 8; ++j) {
            const float ev = bl0[j] * es[j];
            a1 += bl0[j] * ts[j];
            a2 += ev * (lb[j] + lPi[j]);
        }
        acc += 0.5f * a1 + a2;
        LD8(lb, &logBt[xvR][0]);
        a1 = 0.f; a2 = 0.f;
        #pragma unroll
        for (int j = 0; j < 8; ++j) {
            const float ev = bl1[j] * es[j];
            a1 += bl1[j] * ts[j];
            a2 += ev * (lb[j] + lPi[j]);
        }
        acc += 0.5f * a1 + a2;
    }

    // ---------- P5: block reduction, out = -ll ----------
    #pragma unroll
    for (int m = 1; m <= 32; m <<= 1) acc += __shfl_xor(acc, m);
    if (lane == 0) red[wv] = acc;
    __syncthreads();
    if (tid == 0) out[blockIdx.x] = -(red[0] + red[1] + red[2] + red[3]);
}
} // namespace

extern "C" void kernel_launch(void* const* d_in, const int* in_sizes, int n_in,
                              void* d_out, int out_size, void* d_ws, size_t ws_size,
                              hipStream_t stream) {
    const float* A  = (const float*)d_in[0];
    const float* Bm = (const float*)d_in[1];
    const float* Pi = (const float*)d_in[2];
    const int*   x  = (const int*)d_in[3];
    float* o = (float*)d_out;
    hipLaunchKernelGGL(htmm_fused, dim3(64 * 8), dim3(NT), 0, stream,
                       A, Bm, Pi, x, o);
}

// Round 16
// 76.825 us; speedup vs baseline: 1.1717x; 1.0152x over previous
//
#include <hip/hip_runtime.h>

#define NT 256

namespace {
constexpr int C = 8, G = 8, M = 256, NPT = 1023;
constexpr int PD = 12;   // padded per-node float stride (48 B), float4-aligned

__device__ __forceinline__ float rcpf(float x) { return __builtin_amdgcn_rcpf(x); }

__device__ __forceinline__ unsigned short f2b(float f) {   // f32 -> bf16 (RNE)
    union { float f; unsigned int u; } v; v.f = f;
    unsigned int r = v.u + 0x7FFFu + ((v.u >> 16) & 1u);
    return (unsigned short)(r >> 16);
}
__device__ __forceinline__ float2 up2(unsigned int p) {    // packed 2xbf16 -> 2xf32
    union { float f; unsigned int u; } a, b;
    a.u = (p & 0xFFFFu) << 16; b.u = p & 0xFFFF0000u;
    return make_float2(a.f, b.f);
}

#define LD8(dst, srcp) do {                                              \
    const float4 _a = *(const float4*)(srcp);                            \
    const float4 _b = *(const float4*)((srcp) + 4);                      \
    (dst)[0]=_a.x;(dst)[1]=_a.y;(dst)[2]=_a.z;(dst)[3]=_a.w;             \
    (dst)[4]=_b.x;(dst)[5]=_b.y;(dst)[6]=_b.z;(dst)[7]=_b.w; } while(0)

#define ST8(dstp, src) do {                                              \
    *(float4*)(dstp)       = make_float4((src)[0],(src)[1],(src)[2],(src)[3]); \
    *(float4*)((dstp) + 4) = make_float4((src)[4],(src)[5],(src)[6],(src)[7]); } while(0)

__global__ __launch_bounds__(NT, 2)
void htmm_fused(const float* __restrict__ Ag, const float* __restrict__ Bg,
                const float* __restrict__ Pig, const int* __restrict__ xg,
                float* __restrict__ out)
{
    __shared__ int xs[NPT + 1];
    __shared__ __align__(16) float smBt[M][PD];    // softmax(B)^T : [symbol][state]
    __shared__ __align__(16) float logBt[M][PD];   // log softmax(B)^T
    __shared__ __align__(16) float bet[511][PD];   // beta 0..510; eps in place downward
    __shared__ __align__(16) float tbe[255][PD];   // t_beta 0..254
    __shared__ __align__(16) float smA_s[C][C];    // f32, read once to build reg copy
    __shared__ __align__(16) unsigned short alab[C][C]; // bf16 A*logA rows (16B each)
    __shared__ float pi_s[2][C];
    __shared__ float red[4];

    const int tid  = threadIdx.x;
    const int wv   = tid >> 6, lane = tid & 63;
    const int tree = blockIdx.x >> 3, g = blockIdx.x & 7;

    // ---------- P0: stage x, build tables ----------
    for (int n = tid; n < NPT; n += NT) xs[n] = xg[tree * NPT + n];
    {   // emission rows: wave wv owns rows 2wv, 2wv+1; raw in [-5,5]
        const int i  = 2 * wv + (lane >> 5);
        const int c0 = lane & 31;
        float raw[8], ex[8], ssum = 0.f;
        #pragma unroll
        for (int t = 0; t < 8; ++t) {
            raw[t] = Bg[(i * M + c0 + 32 * t) * G + g];
            ex[t]  = __expf(raw[t]);
            ssum  += ex[t];
        }
        #pragma unroll
        for (int m = 1; m <= 16; m <<= 1) ssum += __shfl_xor(ssum, m);
        const float inv = rcpf(ssum), ls = __logf(ssum);
        #pragma unroll
        for (int t = 0; t < 8; ++t) {
            smBt [c0 + 32 * t][i] = ex[t] * inv;
            logBt[c0 + 32 * t][i] = raw[t] - ls;
        }
    }
    if (wv == 0) {                       // A softmax over parent dim i; lane=(i,j)
        const int si = lane >> 3, qj = lane & 7;
        const float raw = Ag[(si * C + qj) * G + g];
        float e = __expf(raw), S = e;
        #pragma unroll
        for (int m = 8; m <= 32; m <<= 1) S += __shfl_xor(S, m);
        const float v = e / S;
        smA_s[si][qj] = v;
        alab[si][qj]  = f2b(v * (raw - __logf(S)));   // bf16 A*logA
    } else if (wv == 1 && lane < C) {    // Pi softmax
        const float raw = Pig[lane * G + g];
        float e = __expf(raw), S = e;
        #pragma unroll
        for (int m = 1; m <= 4; m <<= 1) S += __shfl_xor(S, m);
        pi_s[0][lane] = e / S;
        pi_s[1][lane] = raw - __logf(S);
    }
    __syncthreads();

    // ---------- per-thread A matrix, packed bf16 (32 VGPRs, one-time build) ----------
    unsigned int Apk[32];                // Apk[i*4+jj] = {A[i][2jj], A[i][2jj+1]}
    #pragma unroll
    for (int i = 0; i < 8; ++i) {
        float r[8]; LD8(r, &smA_s[i][0]);
        #pragma unroll
        for (int jj = 0; jj < 4; ++jj)
            Apk[i*4+jj] = (unsigned int)f2b(r[2*jj]) |
                          ((unsigned int)f2b(r[2*jj+1]) << 16);
    }

    // register-only: tb[i] = 0.5 * dot(Arow_i, c8)
    auto trans_up = [&](const float* c8, float* tb) {
        #pragma unroll
        for (int i = 0; i < 8; ++i) {
            float t = 0.f;
            #pragma unroll
            for (int jj = 0; jj < 4; ++jj) {
                const float2 a = up2(Apk[i*4+jj]);
                t += a.x * c8[2*jj] + a.y * c8[2*jj+1];
            }
            tb[i] = 0.5f * t;
        }
    };
    // es = A^T w (registers); ts = (A.logA)^T w (bf16 LDS rows, 1 b128 each)
    auto wexp = [&](const float* w, float* es, float* ts) {
        #pragma unroll
        for (int j = 0; j < 8; ++j) { es[j] = 0.f; ts[j] = 0.f; }
        #pragma unroll
        for (int i = 0; i < 8; ++i) {
            #pragma unroll
            for (int jj = 0; jj < 4; ++jj) {
                const float2 a = up2(Apk[i*4+jj]);
                es[2*jj]   += w[i] * a.x;
                es[2*jj+1] += w[i] * a.y;
            }
            const uint4 lr = *(const uint4*)&alab[i][0];
            const float2 l0 = up2(lr.x), l1 = up2(lr.y), l2 = up2(lr.z), l3 = up2(lr.w);
            ts[0] += w[i]*l0.x; ts[1] += w[i]*l0.y;
            ts[2] += w[i]*l1.x; ts[3] += w[i]*l1.y;
            ts[4] += w[i]*l2.x; ts[5] += w[i]*l2.y;
            ts[6] += w[i]*l3.x; ts[7] += w[i]*l3.y;
        }
    };

    float acc = 0.f;

    // ---------- P1: bottom subtree (level-8 node + 2 leaves) in registers ----------
    const int nd8 = 255 + tid;
    const int xv8 = xs[nd8], xvL = xs[2*nd8 + 1], xvR = xs[2*nd8 + 2];
    float bl0[8], bl1[8], tb8[8], b8[8];
    {
        float piR[8]; LD8(piR, &pi_s[0][0]);
        float sm[8], u[8], S, inv;
        LD8(sm, &smBt[xvL][0]);
        S = 0.f;
        #pragma unroll
        for (int i = 0; i < 8; ++i) { u[i] = piR[i] * sm[i]; S += u[i]; }
        inv = rcpf(S);
        #pragma unroll
        for (int i = 0; i < 8; ++i) bl0[i] = u[i] * inv;

        LD8(sm, &smBt[xvR][0]);
        S = 0.f;
        #pragma unroll
        for (int i = 0; i < 8; ++i) { u[i] = piR[i] * sm[i]; S += u[i]; }
        inv = rcpf(S);
        #pragma unroll
        for (int i = 0; i < 8; ++i) bl1[i] = u[i] * inv;

        float c[8];
        #pragma unroll
        for (int j = 0; j < 8; ++j) c[j] = bl0[j] + bl1[j];
        trans_up(c, tb8);
        LD8(sm, &smBt[xv8][0]);
        S = 0.f;
        #pragma unroll
        for (int i = 0; i < 8; ++i) { u[i] = tb8[i] * sm[i]; S += u[i]; }
        inv = rcpf(S);
        #pragma unroll
        for (int i = 0; i < 8; ++i) b8[i] = u[i] * inv;
        ST8(&bet[nd8][0], b8);
    }
    __syncthreads();

    // ---------- P2: upper tree upward, thread-per-node ----------
    for (int lvl = 7; lvl >= 0; --lvl) {
        const int cnt = 1 << lvl, base = cnt - 1;
        if (tid < cnt) {
            const int p = base + tid, cl = 2*p + 1;
            float lb_[8], rb_[8], cb[8], tb[8];
            LD8(lb_, &bet[cl][0]);
            LD8(rb_, &bet[cl + 1][0]);
            #pragma unroll
            for (int j = 0; j < 8; ++j) cb[j] = lb_[j] + rb_[j];
            trans_up(cb, tb);
            ST8(&tbe[p][0], tb);
            float sm[8], u[8], S = 0.f;
            LD8(sm, &smBt[xs[p]][0]);
            #pragma unroll
            for (int i = 0; i < 8; ++i) { u[i] = tb[i] * sm[i]; S += u[i]; }
            const float inv = rcpf(S);
            float b[8];
            #pragma unroll
            for (int i = 0; i < 8; ++i) b[i] = u[i] * inv;
            ST8(&bet[p][0], b);
        }
        __syncthreads();
    }

    if (tid == 0) {                      // root B-term (eps[root] = beta[root])
        float b0[8], lb[8];
        LD8(b0, &bet[0][0]);
        LD8(lb, &logBt[xs[0]][0]);
        #pragma unroll
        for (int j = 0; j < 8; ++j) acc += b0[j] * lb[j];
    }

    // ---------- P3: upper tree downward, thread-per-PARENT ----------
    for (int dc = 1; dc <= 7; ++dc) {
        const int cntp = 1 << (dc - 1), basep = cntp - 1;
        if (tid < cntp) {
            const int p = basep + tid;
            float ep[8], tp[8], w[8], es[8], ts[8];
            LD8(ep, &bet[p][0]);
            LD8(tp, &tbe[p][0]);
            #pragma unroll
            for (int i = 0; i < 8; ++i) w[i] = ep[i] * rcpf(tp[i]);
            wexp(w, es, ts);
            #pragma unroll
            for (int cc = 0; cc < 2; ++cc) {
                const int ch = 2*p + 1 + cc;
                float bc[8], lb[8], ev[8];
                LD8(bc, &bet[ch][0]);
                LD8(lb, &logBt[xs[ch]][0]);
                float a1 = 0.f, a2 = 0.f;
                #pragma unroll
                for (int j = 0; j < 8; ++j) {
                    ev[j] = bc[j] * es[j];
                    a1 += bc[j] * ts[j];
                    a2 += ev[j] * lb[j];
                }
                acc += 0.5f * a1 + a2;
                ST8(&bet[ch][0], ev);    // eps in place
            }
        }
        __syncthreads();
    }

    // ---------- P4: bottom subtree downward, per thread ----------
    {
        const int p7 = (nd8 - 1) >> 1;
        float ep[8], tp[8], w[8], es[8], ts[8];
        LD8(ep, &bet[p7][0]);
        LD8(tp, &tbe[p7][0]);
        #pragma unroll
        for (int i = 0; i < 8; ++i) w[i] = ep[i] * rcpf(tp[i]);
        wexp(w, es, ts);

        float lb[8], ev8[8], w8[8];
        LD8(lb, &logBt[xv8][0]);
        float a1 = 0.f, a2 = 0.f;
        #pragma unroll
        for (int j = 0; j < 8; ++j) {
            ev8[j] = b8[j] * es[j];
            a1 += b8[j] * ts[j];
            a2 += ev8[j] * lb[j];
        }
        acc += 0.5f * a1 + a2;
        #pragma unroll
        for (int i = 0; i < 8; ++i) w8[i] = ev8[i] * rcpf(tb8[i]);

        wexp(w8, es, ts);                // shared by both leaves
        float lPi[8]; LD8(lPi, &pi_s[1][0]);
        LD8(lb, &logBt[xvL][0]);
        a1 = 0.f; a2 = 0.f;
        #pragma unroll
        for (int j = 0; j < 8; ++j) {
            const float ev = bl0[j] * es[j];
            a1 += bl0[j] * ts[j];
            a2 += ev * (lb[j] + lPi[j]);
        }
        acc += 0.5f * a1 + a2;
        LD8(lb, &logBt[xvR][0]);
        a1 = 0.f; a2 = 0.f;
        #pragma unroll
        for (int j = 0; j < 8; ++j) {
            const float ev = bl1[j] * es[j];
            a1 += bl1[j] * ts[j];
            a2 += ev * (lb[j] + lPi[j]);
        }
        acc += 0.5f * a1 + a2;
    }

    // ---------- P5: block reduction, out = -ll ----------
    #pragma unroll
    for (int m = 1; m <= 32; m <<= 1) acc += __shfl_xor(acc, m);
    if (lane == 0) red[wv] = acc;
    __syncthreads();
    if (tid == 0) out[blockIdx.x] = -(red[0] + red[1] + red[2] + red[3]);
}
} // namespace

extern "C" void kernel_launch(void* const* d_in, const int* in_sizes, int n_in,
                              void* d_out, int out_size, void* d_ws, size_t ws_size,
                              hipStream_t stream) {
    const float* A  = (const float*)d_in[0];
    const float* Bm = (const float*)d_in[1];
    const float* Pi = (const float*)d_in[2];
    const int*   x  = (const int*)d_in[3];
    float* o = (float*)d_out;
    hipLaunchKernelGGL(htmm_fused, dim3(64 * 8), dim3(NT), 0, stream,
                       A, Bm, Pi, x, o);
}